// Round 3
// baseline (2978.755 us; speedup 1.0000x reference)
//
#include <hip/hip_runtime.h>
#include <hip/hip_bf16.h>
#include <cstdint>
#include <cstdio>

#define B_ 2
#define T_ 1024
#define V_ 32000
#define D_ 1024
#define H_ 16
#define HD_ 64
#define L_ 8
#define FF_ 4096
#define NM_ 66
#define S_ 1090
#define SP_ 1152   // padded seq for attention tiles (multiple of 64, >= 18*64)
#define M_ 2180    // B_*S_
#define MP_ 2304   // padded rows (18*128)
#define MT_ 2048   // B_*T_

typedef __bf16 bf16_t;
typedef __bf16 bf16x8 __attribute__((ext_vector_type(8)));
typedef __bf16 bf16x4v __attribute__((ext_vector_type(4)));
typedef float f32x4 __attribute__((ext_vector_type(4)));

// ---------------- small utility kernels ----------------

__global__ void k_costab(float* __restrict__ cosT, float* __restrict__ sinT) {
  int i = blockIdx.x * 256 + threadIdx.x;
  if (i >= S_ * 32) return;
  int pos = i >> 5, f = i & 31;
  float fr = powf(10000.0f, -(float)f / 32.0f);
  float a = (float)pos * fr;
  cosT[i] = cosf(a);
  sinT[i] = sinf(a);
}

__global__ void k_cast4(const float* __restrict__ s, bf16_t* __restrict__ d, int n4) {
  int i = blockIdx.x * 256 + threadIdx.x;
  int st = gridDim.x * 256;
  for (; i < n4; i += st) {
    float4 v = ((const float4*)s)[i];
    ((bf16x4v*)d)[i] = (bf16x4v){(bf16_t)v.x, (bf16_t)v.y, (bf16_t)v.z, (bf16_t)v.w};
  }
}

// transpose fp32 (R x C) -> bf16 (C x R)
__global__ void k_transpose(const float* __restrict__ src, bf16_t* __restrict__ dst,
                            int R, int C) {
  __shared__ float tile[32][33];
  int c0 = blockIdx.x * 32, r0 = blockIdx.y * 32;
  int tx = threadIdx.x, ty = threadIdx.y;
  #pragma unroll
  for (int i = 0; i < 4; i++)
    tile[ty + i * 8][tx] = src[(long)(r0 + ty + i * 8) * C + c0 + tx];
  __syncthreads();
  #pragma unroll
  for (int i = 0; i < 4; i++)
    dst[(long)(c0 + ty + i * 8) * R + r0 + tx] = (bf16_t)tile[tx][ty + i * 8];
}

// per-layer Wq/Wk/Wv (1024,1024 each) -> dst[sel*1024 + n][k]
__global__ void k_transpose_qkv(const float* __restrict__ Wq, const float* __restrict__ Wk,
                                const float* __restrict__ Wv, bf16_t* __restrict__ dst) {
  __shared__ float tile[32][33];
  int sel = blockIdx.z;
  const float* src = (sel == 0 ? Wq : (sel == 1 ? Wk : Wv));
  bf16_t* d = dst + (long)sel * D_ * D_;
  int c0 = blockIdx.x * 32, r0 = blockIdx.y * 32;
  int tx = threadIdx.x, ty = threadIdx.y;
  #pragma unroll
  for (int i = 0; i < 4; i++)
    tile[ty + i * 8][tx] = src[(long)(r0 + ty + i * 8) * D_ + c0 + tx];
  __syncthreads();
  #pragma unroll
  for (int i = 0; i < 4; i++)
    d[(long)(c0 + ty + i * 8) * D_ + r0 + tx] = (bf16_t)tile[tx][ty + i * 8];
}

__global__ void k_build_x(const int* __restrict__ tok, const float* __restrict__ mem,
                          const float* __restrict__ embed, float* __restrict__ x) {
  int r = blockIdx.x;
  int b = r / S_, s = r % S_;
  const float* src;
  if (s == 0)        src = embed + 1l * D_;                 // MEM_START id = 1
  else if (s <= 64)  src = mem + ((long)b * 64 + (s - 1)) * D_;
  else if (s == 65)  src = embed + 2l * D_;                 // MEM_END id = 2
  else               src = embed + (long)tok[b * T_ + (s - 66)] * D_;
  ((float4*)(x + (long)r * D_))[threadIdx.x] = ((const float4*)src)[threadIdx.x];
}

__device__ __forceinline__ float blockSum256(float v) {
  #pragma unroll
  for (int m = 1; m < 64; m <<= 1) v += __shfl_xor(v, m);
  __shared__ float red[4];
  __syncthreads();
  if ((threadIdx.x & 63) == 0) red[threadIdx.x >> 6] = v;
  __syncthreads();
  return red[0] + red[1] + red[2] + red[3];
}

__global__ void k_rms(const float* __restrict__ x, const float* __restrict__ w,
                      bf16_t* __restrict__ o) {
  int r = blockIdx.x, t = threadIdx.x;
  bf16x4v* o4 = ((bf16x4v*)(o + (long)r * D_)) + t;
  if (r >= M_) {  // zero pad rows so GEMM A-tiles are clean
    *o4 = (bf16x4v){(bf16_t)0.f, (bf16_t)0.f, (bf16_t)0.f, (bf16_t)0.f};
    return;
  }
  float4 v = ((const float4*)(x + (long)r * D_))[t];
  float ss = blockSum256(v.x * v.x + v.y * v.y + v.z * v.z + v.w * v.w);
  float nr = rsqrtf(ss * (1.0f / D_) + 1e-8f);
  float4 wv = ((const float4*)w)[t];
  *o4 = (bf16x4v){(bf16_t)(v.x * nr * wv.x), (bf16_t)(v.y * nr * wv.y),
                  (bf16_t)(v.z * nr * wv.z), (bf16_t)(v.w * nr * wv.w)};
}

__global__ void k_final_text(const float* __restrict__ x, const float* __restrict__ w,
                             bf16_t* __restrict__ o) {
  int r = blockIdx.x, t = threadIdx.x;
  int b = r / S_, s = r % S_;
  if (s < NM_) return;  // uniform per block
  float4 v = ((const float4*)(x + (long)r * D_))[t];
  float ss = blockSum256(v.x * v.x + v.y * v.y + v.z * v.z + v.w * v.w);
  float nr = rsqrtf(ss * (1.0f / D_) + 1e-8f);
  float4 wv = ((const float4*)w)[t];
  long orow = (long)b * T_ + (s - NM_);
  ((bf16x4v*)(o + orow * D_))[t] =
      (bf16x4v){(bf16_t)(v.x * nr * wv.x), (bf16_t)(v.y * nr * wv.y),
                (bf16_t)(v.z * nr * wv.z), (bf16_t)(v.w * nr * wv.w)};
}

__global__ void k_halt(const float* __restrict__ x, const float* __restrict__ fnw,
                       const float* __restrict__ hW, const float* __restrict__ hb,
                       float* __restrict__ out) {
  int b = blockIdx.x, t = threadIdx.x;
  long r = (long)b * S_ + (S_ - 1);
  float4 v = ((const float4*)(x + r * D_))[t];
  float ss = blockSum256(v.x * v.x + v.y * v.y + v.z * v.z + v.w * v.w);
  float nr = rsqrtf(ss * (1.0f / D_) + 1e-8f);
  float4 wv = ((const float4*)fnw)[t];
  float xn0 = v.x * nr * wv.x, xn1 = v.y * nr * wv.y, xn2 = v.z * nr * wv.z, xn3 = v.w * nr * wv.w;
  float4 h0 = ((const float4*)hW)[t];
  float4 h1 = ((const float4*)(hW + D_))[t];
  float d0 = xn0 * h0.x + xn1 * h0.y + xn2 * h0.z + xn3 * h0.w;
  float d1 = xn0 * h1.x + xn1 * h1.y + xn2 * h1.z + xn3 * h1.w;
  d0 = blockSum256(d0);
  d1 = blockSum256(d1);
  if (t == 0) {
    out[(long)B_ * T_ * V_ + b * 2 + 0] = d0 + hb[0];
    out[(long)B_ * T_ * V_ + b * 2 + 1] = d1 + hb[1];
  }
}

// rope: qkv fp32 (MP,3072) -> q_r/k_r bf16 (B,H,SP,HD), zero pad rows
__global__ void k_rope(const float* __restrict__ qkv, const float* __restrict__ cosT,
                       const float* __restrict__ sinT, bf16_t* __restrict__ qr,
                       bf16_t* __restrict__ kr) {
  int s = blockIdx.x, h = blockIdx.y, b = blockIdx.z;
  int t = threadIdx.x;
  int half = t >> 5, d = t & 31;
  bf16_t* dst = (half ? kr : qr) + ((long)(b * H_ + h) * SP_ + s) * HD_;
  float o1 = 0.f, o2 = 0.f;
  if (s < S_) {
    long row = (long)b * S_ + s;
    const float* src = qkv + row * 3072 + half * 1024 + h * 64;
    float x1 = src[d], x2 = src[d + 32];
    float c = cosT[s * 32 + d], sn = sinT[s * 32 + d];
    o1 = x1 * c - x2 * sn;
    o2 = x1 * sn + x2 * c;
  }
  dst[d] = (bf16_t)o1;
  dst[d + 32] = (bf16_t)o2;
}

// v transpose: qkv fp32 (.,2048+h*64+d) -> v_t bf16 (B,H,HD,SP), zero pad cols
__global__ void k_vt(const float* __restrict__ qkv, bf16_t* __restrict__ vt) {
  __shared__ float tile[32][33];
  int bh = blockIdx.z;
  int b = bh >> 4, h = bh & 15;
  int s0 = blockIdx.x * 32, d0 = blockIdx.y * 32;
  int tx = threadIdx.x, ty = threadIdx.y;
  #pragma unroll
  for (int i = 0; i < 4; i++) {
    int s = s0 + ty + i * 8;
    tile[ty + i * 8][tx] = (s < S_) ? qkv[((long)(b * S_ + s)) * 3072 + 2048 + h * 64 + d0 + tx] : 0.f;
  }
  __syncthreads();
  #pragma unroll
  for (int i = 0; i < 4; i++) {
    int d = d0 + ty + i * 8;
    vt[((long)bh * HD_ + d) * SP_ + s0 + tx] = (bf16_t)tile[tx][ty + i * 8];
  }
}

// ---------------- GEMM: C(MxN) = A(MxK,bf16) @ Bt(NxK,bf16)^T ----------------
// MODE 0: store f32   1: add into f32   3: silu -> bf16
template <int MODE>
__global__ __launch_bounds__(256) void k_gemm(const bf16_t* __restrict__ A,
                                              const bf16_t* __restrict__ Bt,
                                              float* __restrict__ Cf,
                                              bf16_t* __restrict__ Cb, int N, int K) {
  __shared__ bf16_t As[128 * 32];
  __shared__ bf16_t Bs[128 * 32];
  const int t = threadIdx.x;
  const int lane = t & 63;
  const int wave = t >> 6;
  const int wr = wave >> 1, wc = wave & 1;
  const long bm = (long)blockIdx.x * 128;
  const long bn = (long)blockIdx.y * 128;
  const bf16_t* Ab = A + bm * K;
  const bf16_t* Bb = Bt + bn * K;

  f32x4 acc[4][4] = {};

  // staging assignment: thread handles flat16 ids {t, t+256} for both A and B
  const int f0 = t, f1 = t + 256;
  const int r0 = f0 >> 2, sl0 = f0 & 3;
  const int r1 = f1 >> 2, sl1 = f1 & 3;
  const int w0 = r0 * 32 + ((sl0 ^ ((r0 >> 1) & 3)) * 8);  // swizzled LDS elem offset
  const int w1 = r1 * 32 + ((sl1 ^ ((r1 >> 1) & 3)) * 8);
  const long g0 = (long)r0 * K + sl0 * 8;
  const long g1 = (long)r1 * K + sl1 * 8;

  bf16x8 ra0 = *(const bf16x8*)(Ab + g0);
  bf16x8 ra1 = *(const bf16x8*)(Ab + g1);
  bf16x8 rb0 = *(const bf16x8*)(Bb + g0);
  bf16x8 rb1 = *(const bf16x8*)(Bb + g1);

  const int l15 = lane & 15, kg = lane >> 4;

  for (int k0 = 0; k0 < K; k0 += 32) {
    *(bf16x8*)(As + w0) = ra0;
    *(bf16x8*)(As + w1) = ra1;
    *(bf16x8*)(Bs + w0) = rb0;
    *(bf16x8*)(Bs + w1) = rb1;
    __syncthreads();
    if (k0 + 32 < K) {  // prefetch next K-tile while computing
      ra0 = *(const bf16x8*)(Ab + g0 + k0 + 32);
      ra1 = *(const bf16x8*)(Ab + g1 + k0 + 32);
      rb0 = *(const bf16x8*)(Bb + g0 + k0 + 32);
      rb1 = *(const bf16x8*)(Bb + g1 + k0 + 32);
    }
    bf16x8 af[4], bfr[4];
    #pragma unroll
    for (int i = 0; i < 4; i++) {
      int rowA = wr * 64 + i * 16 + l15;
      af[i] = *(const bf16x8*)(As + rowA * 32 + ((kg ^ ((rowA >> 1) & 3)) * 8));
      int rowB = wc * 64 + i * 16 + l15;
      bfr[i] = *(const bf16x8*)(Bs + rowB * 32 + ((kg ^ ((rowB >> 1) & 3)) * 8));
    }
    #pragma unroll
    for (int i = 0; i < 4; i++)
      #pragma unroll
      for (int j = 0; j < 4; j++)
        acc[i][j] = __builtin_amdgcn_mfma_f32_16x16x32_bf16(af[i], bfr[j], acc[i][j], 0, 0, 0);
    __syncthreads();
  }

  #pragma unroll
  for (int i = 0; i < 4; i++) {
    #pragma unroll
    for (int j = 0; j < 4; j++) {
      long r = bm + wr * 64 + i * 16 + kg * 4;
      long c = bn + wc * 64 + j * 16 + l15;
      #pragma unroll
      for (int q = 0; q < 4; q++) {
        long idx = (r + q) * (long)N + c;
        float v = acc[i][j][q];
        if constexpr (MODE == 0) {
          Cf[idx] = v;
        } else if constexpr (MODE == 1) {
          Cf[idx] += v;
        } else {
          float sv = v / (1.f + __expf(-v));
          Cb[idx] = (bf16_t)sv;
        }
      }
    }
  }
}

// ---------------- flash attention ----------------
// q_r/k_r: (B,H,SP,HD) bf16 (rope applied, zero-padded); v_t: (B,H,HD,SP) bf16
// out: o_bf (MP,D) bf16 rows b*S_+s
__global__ __launch_bounds__(256) void k_attn(const bf16_t* __restrict__ qr,
                                              const bf16_t* __restrict__ kr,
                                              const bf16_t* __restrict__ vt,
                                              bf16_t* __restrict__ obf) {
  __shared__ bf16_t Pl[4 * 16 * 32];
  const int qt = blockIdx.x, h = blockIdx.y, b = blockIdx.z;
  const int t = threadIdx.x, lane = t & 63, wid = t >> 6;
  const int bh = b * H_ + h;
  const bf16_t* qb = qr + (long)bh * SP_ * HD_;
  const bf16_t* kb = kr + (long)bh * SP_ * HD_;
  const bf16_t* vb = vt + (long)bh * HD_ * SP_;
  const int qrow16 = qt * 64 + wid * 16;
  const int l15 = lane & 15, kg = lane >> 4;

  bf16x8 qf[2];
  {
    int qrow = qrow16 + l15;
    qf[0] = *(const bf16x8*)(qb + (long)qrow * HD_ + kg * 8);
    qf[1] = *(const bf16x8*)(qb + (long)qrow * HD_ + 32 + kg * 8);
  }

  float m_run[4], l_run[4];
  f32x4 o_acc[4] = {};
  #pragma unroll
  for (int r2 = 0; r2 < 4; r2++) { m_run[r2] = -INFINITY; l_run[r2] = 0.f; }

  int irow[4];
  #pragma unroll
  for (int r2 = 0; r2 < 4; r2++) irow[r2] = qrow16 + kg * 4 + r2;

  const int qend = min(qt * 64 + 63, S_ - 1);
  const int kmax = max(NM_, qend + 1);
  bf16_t* Pw = Pl + wid * 512;

  for (int s0 = 0; s0 < kmax; s0 += 32) {
    f32x4 sc[2] = {};
    #pragma unroll
    for (int n = 0; n < 2; n++) {
      int krow = s0 + n * 16 + l15;
      bf16x8 kf0 = *(const bf16x8*)(kb + (long)krow * HD_ + kg * 8);
      bf16x8 kf1 = *(const bf16x8*)(kb + (long)krow * HD_ + 32 + kg * 8);
      sc[n] = __builtin_amdgcn_mfma_f32_16x16x32_bf16(qf[0], kf0, sc[n], 0, 0, 0);
      sc[n] = __builtin_amdgcn_mfma_f32_16x16x32_bf16(qf[1], kf1, sc[n], 0, 0, 0);
    }
    // mask + scale
    #pragma unroll
    for (int n = 0; n < 2; n++) {
      int j = s0 + n * 16 + l15;
      #pragma unroll
      for (int r2 = 0; r2 < 4; r2++) {
        int i = irow[r2];
        bool valid = (i < NM_) ? (j < NM_) : (j < NM_ || j <= i);
        sc[n][r2] = valid ? sc[n][r2] * 0.125f : -INFINITY;
      }
    }
    float p[2][4];
    #pragma unroll
    for (int r2 = 0; r2 < 4; r2++) {
      float mx = fmaxf(sc[0][r2], sc[1][r2]);
      mx = fmaxf(mx, __shfl_xor(mx, 1));
      mx = fmaxf(mx, __shfl_xor(mx, 2));
      mx = fmaxf(mx, __shfl_xor(mx, 4));
      mx = fmaxf(mx, __shfl_xor(mx, 8));
      float mn = fmaxf(m_run[r2], mx);
      float al = __expf(m_run[r2] - mn);  // first tile: exp(-inf)=0
      m_run[r2] = mn;
      float ps = 0.f;
      #pragma unroll
      for (int n = 0; n < 2; n++) {
        float pv = __expf(sc[n][r2] - mn);  // masked -> exp(-inf)=0
        p[n][r2] = pv;
        ps += pv;
      }
      ps += __shfl_xor(ps, 1);
      ps += __shfl_xor(ps, 2);
      ps += __shfl_xor(ps, 4);
      ps += __shfl_xor(ps, 8);
      l_run[r2] = l_run[r2] * al + ps;
      #pragma unroll
      for (int tt = 0; tt < 4; tt++) o_acc[tt][r2] *= al;
    }
    // P -> LDS (swizzled), then read as MFMA-A fragment
    #pragma unroll
    for (int n = 0; n < 2; n++)
      #pragma unroll
      for (int r2 = 0; r2 < 4; r2++) {
        int row = kg * 4 + r2;
        int colx = (n * 16 + l15) ^ (((row >> 1) & 3) << 3);
        Pw[row * 32 + colx] = (bf16_t)p[n][r2];
      }
    bf16x8 pf;
    {
      int row = l15;
      int colx = (kg * 8) ^ (((row >> 1) & 3) << 3);
      pf = *(const bf16x8*)(Pw + row * 32 + colx);
    }
    #pragma unroll
    for (int tt = 0; tt < 4; tt++) {
      bf16x8 vf = *(const bf16x8*)(vb + (long)(tt * 16 + l15) * SP_ + s0 + kg * 8);
      o_acc[tt] = __builtin_amdgcn_mfma_f32_16x16x32_bf16(pf, vf, o_acc[tt], 0, 0, 0);
    }
  }

  #pragma unroll
  for (int r2 = 0; r2 < 4; r2++) {
    int row = qrow16 + kg * 4 + r2;
    if (row < S_) {
      float inv = 1.0f / l_run[r2];
      #pragma unroll
      for (int tt = 0; tt < 4; tt++)
        obf[((long)(b * S_ + row)) * D_ + h * 64 + tt * 16 + l15] = (bf16_t)(o_acc[tt][r2] * inv);
    }
  }
}

// ---------------- host orchestration ----------------

extern "C" void kernel_launch(void* const* d_in, const int* in_sizes, int n_in,
                              void* d_out, int out_size, void* d_ws, size_t ws_size,
                              hipStream_t stream) {
  const int*   tok   = (const int*)  d_in[0];
  const float* mem   = (const float*)d_in[1];
  const float* embed = (const float*)d_in[2];
  const float* Wq    = (const float*)d_in[3];
  const float* Wk    = (const float*)d_in[4];
  const float* Wv    = (const float*)d_in[5];
  const float* Wo    = (const float*)d_in[6];
  const float* n1w   = (const float*)d_in[7];
  const float* n2w   = (const float*)d_in[8];
  const float* Wup   = (const float*)d_in[9];
  const float* Wdn   = (const float*)d_in[10];
  const float* fnw   = (const float*)d_in[11];
  const float* hW    = (const float*)d_in[12];
  const float* hb    = (const float*)d_in[13];
  float* out = (float*)d_out;

  char* p = (char*)d_ws;
  auto alloc = [&](size_t bytes) -> void* {
    void* r = (void*)p;
    p += (bytes + 255) & ~(size_t)255;
    return r;
  };
  float*  cosT   = (float*) alloc((size_t)S_ * 32 * 4);
  float*  sinT   = (float*) alloc((size_t)S_ * 32 * 4);
  float*  x      = (float*) alloc((size_t)MP_ * D_ * 4);
  bf16_t* hBf    = (bf16_t*)alloc((size_t)MP_ * D_ * 2);
  float*  qkv    = (float*) alloc((size_t)MP_ * 3 * D_ * 4);
  bf16_t* qR     = (bf16_t*)alloc((size_t)B_ * H_ * SP_ * HD_ * 2);
  bf16_t* kR     = (bf16_t*)alloc((size_t)B_ * H_ * SP_ * HD_ * 2);
  bf16_t* vT     = (bf16_t*)alloc((size_t)B_ * H_ * HD_ * SP_ * 2);
  bf16_t* oBf    = (bf16_t*)alloc((size_t)MP_ * D_ * 2);
  bf16_t* ffa    = (bf16_t*)alloc((size_t)MP_ * FF_ * 2);
  bf16_t* textBf = (bf16_t*)alloc((size_t)MT_ * D_ * 2);
  bf16_t* embBf  = (bf16_t*)alloc((size_t)V_ * D_ * 2);
  // per-layer transposed weights (reused each layer): qkv | wo | wup | wdn
  bf16_t* wBt    = (bf16_t*)alloc(((size_t)3 * D_ * D_ + (size_t)D_ * D_ +
                                   (size_t)FF_ * D_ + (size_t)D_ * FF_) * 2);
  bf16_t* wqkvBt = wBt;
  bf16_t* woBt   = wBt + (size_t)3 * D_ * D_;
  bf16_t* wupBt  = woBt + (size_t)D_ * D_;
  bf16_t* wdnBt  = wupBt + (size_t)FF_ * D_;

  size_t needed = (size_t)(p - (char*)d_ws);
  if (needed > ws_size) {
    fprintf(stderr, "kernel_launch: workspace too small: need %zu, have %zu\n", needed, ws_size);
    return;
  }

  dim3 b256(256);
  // one-time-per-call prep
  k_costab<<<dim3((S_ * 32 + 255) / 256), b256, 0, stream>>>(cosT, sinT);
  k_cast4<<<dim3(8192), b256, 0, stream>>>(embed, embBf, V_ * D_ / 4);
  k_build_x<<<dim3(M_), b256, 0, stream>>>(tok, mem, embed, x);

  for (int l = 0; l < L_; l++) {
    // per-layer weight prep (stream-ordered; buffer reused across layers)
    k_transpose_qkv<<<dim3(32, 32, 3), dim3(32, 8), 0, stream>>>(
        Wq + (long)l * D_ * D_, Wk + (long)l * D_ * D_, Wv + (long)l * D_ * D_, wqkvBt);
    k_transpose<<<dim3(32, 32),  dim3(32, 8), 0, stream>>>(Wo  + (long)l * D_ * D_,  woBt,  1024, 1024);
    k_transpose<<<dim3(128, 32), dim3(32, 8), 0, stream>>>(Wup + (long)l * D_ * FF_, wupBt, 1024, 4096);
    k_transpose<<<dim3(32, 128), dim3(32, 8), 0, stream>>>(Wdn + (long)l * FF_ * D_, wdnBt, 4096, 1024);

    k_rms<<<dim3(MP_), b256, 0, stream>>>(x, n1w + l * D_, hBf);
    k_gemm<0><<<dim3(18, 24), b256, 0, stream>>>(hBf, wqkvBt, qkv, nullptr, 3072, 1024);
    k_rope<<<dim3(SP_, H_, B_), dim3(64), 0, stream>>>(qkv, cosT, sinT, qR, kR);
    k_vt<<<dim3(SP_ / 32, 2, B_ * H_), dim3(32, 8), 0, stream>>>(qkv, vT);
    k_attn<<<dim3(18, H_, B_), b256, 0, stream>>>(qR, kR, vT, oBf);
    k_gemm<1><<<dim3(18, 8), b256, 0, stream>>>(oBf, woBt, x, nullptr, 1024, 1024);
    k_rms<<<dim3(MP_), b256, 0, stream>>>(x, n2w + l * D_, hBf);
    k_gemm<3><<<dim3(18, 32), b256, 0, stream>>>(hBf, wupBt, nullptr, ffa, 4096, 1024);
    k_gemm<1><<<dim3(18, 8), b256, 0, stream>>>(ffa, wdnBt, x, nullptr, 1024, 4096);
  }

  k_final_text<<<dim3(M_), b256, 0, stream>>>(x, fnw, textBf);
  k_gemm<0><<<dim3(16, 250), b256, 0, stream>>>(textBf, embBf, out, nullptr, V_, 1024);
  k_halt<<<dim3(B_), b256, 0, stream>>>(x, fnw, hW, hb, out);
}